// Round 5
// baseline (237.795 us; speedup 1.0000x reference)
//
#include <hip/hip_runtime.h>
#include <hip/hip_bf16.h>
#include <cmath>

// Problem constants
#define Bc   32
#define Sc_  512
#define Hc   768
#define NHc  12
#define DHc  64
#define Mc   (Bc * Sc_)     // 16384 tokens
#define Ntot (3 * Hc)       // 2304 fused output cols (Q|K|V)

// 0.125 (1/sqrt(DH)) * log2(e): folded into Q so softmax is exp2(s)
#define QSCALE 0.18033688011112042f

typedef __attribute__((ext_vector_type(8))) short short8v;   // 8 bf16 (4 VGPRs)
typedef __attribute__((ext_vector_type(8))) unsigned short ushort8v;
typedef __attribute__((ext_vector_type(4))) float f32x4;     // MFMA acc

static __device__ __forceinline__ ushort f2b(float f) {
    __hip_bfloat16 h = __float2bfloat16(f);
    return *reinterpret_cast<ushort*>(&h);
}
static __device__ __forceinline__ ushort2 f2b2(float a, float b) {
    __hip_bfloat162 h = __float22bfloat162_rn(float2{a, b});
    return *reinterpret_cast<ushort2*>(&h);
}

// tanh(x) = 1 - 2/(exp2(2x*log2e)+1); exact at +/-inf via rcp(inf)=0
static __device__ __forceinline__ float fast_tanh(float x) {
    float e = __builtin_amdgcn_exp2f(x * 2.885390081777927f);
    return 1.0f - 2.0f * __builtin_amdgcn_rcpf(e + 1.0f);
}

// ---------------------------------------------------------------------------
// Kernel 0 (R0 exact, verified): fp32 -> bf16 tiled repack.
//   Xt [m/128][k/8][m%128][8], Wt [n/128][k/8][n%128][8].
// ---------------------------------------------------------------------------
__global__ __launch_bounds__(256) void convert_pack(
    const float* __restrict__ X,
    const float* __restrict__ Wq, const float* __restrict__ Wk,
    const float* __restrict__ Wv,
    const float* __restrict__ bq, const float* __restrict__ bk,
    const float* __restrict__ bv,
    ushort* __restrict__ Xt, ushort* __restrict__ Wt, float* __restrict__ bbp)
{
    const int bx = blockIdx.x;
    const int panel = bx / 12, kcg = bx % 12;   // kcg = 64-k group
    const int t = threadIdx.x;

    __shared__ ushort T[128][68];

    const float* base;
    ushort* out;
    if (panel < 128) {
        base = X + (size_t)panel * 128 * Hc;
        out  = Xt + (size_t)panel * (96 * 1024);
    } else {
        int nblk = panel - 128;                 // 0..17
        int n0 = nblk * 128;
        int z = n0 / Hc;
        int nn0 = n0 - z * Hc;
        const float* W = (z == 0) ? Wq : (z == 1) ? Wk : Wv;
        base = W + (size_t)nn0 * Hc;
        out  = Wt + (size_t)nblk * (96 * 1024);
    }
    const int k0 = kcg * 64;

    const int slot = t & 15, rsub = t >> 4;
    #pragma unroll
    for (int rnd = 0; rnd < 8; ++rnd) {
        int row = rnd * 16 + rsub;
        const float* p = base + (size_t)row * Hc + k0 + slot * 4;
        float4 f = *(const float4*)p;
        ushort2 h0 = f2b2(f.x, f.y);
        ushort2 h1 = f2b2(f.z, f.w);
        ushort4 u;
        u.x = h0.x; u.y = h0.y; u.z = h1.x; u.w = h1.y;
        *(ushort4*)&T[row][slot * 4] = u;
    }
    __syncthreads();

    const int row_w = t & 127, kh = t >> 7;
    #pragma unroll
    for (int rnd = 0; rnd < 4; ++rnd) {
        int kc_l = rnd * 2 + kh;
        ushort4 lo = *(const ushort4*)&T[row_w][kc_l * 8];
        ushort4 hi = *(const ushort4*)&T[row_w][kc_l * 8 + 4];
        ushort8v o;
        o[0] = lo.x; o[1] = lo.y; o[2] = lo.z; o[3] = lo.w;
        o[4] = hi.x; o[5] = hi.y; o[6] = hi.z; o[7] = hi.w;
        *(ushort8v*)&out[(size_t)(kcg * 8 + kc_l) * 1024 + row_w * 8] = o;
    }

    if (bx == 0) {
        for (int i = t; i < Ntot; i += 256) {
            int z2 = i / Hc, nn = i - z2 * Hc;
            bbp[i] = ((z2 == 0) ? bq : (z2 == 1) ? bk : bv)[nn];
        }
    }
}

// ---------------------------------------------------------------------------
// Kernel 1 (NEW): fully fused per-(batch,head,q-half) QKV projection +
// attention. 768 blocks x 512 threads, 1 block/CU (144 KiB LDS), 3 rounds.
//
// Phases (3 __syncthreads total; projection k-loops have NO barriers):
//  1. Q-proj (256 q x 64 d, K=768): A/B frags DIRECT from packed Xt/Wt
//     (same fragment address math as the verified R0 GEMM, global-sourced).
//     Epilogue -> LDS scratch in Qb layout [q][d] (scaled), bounce to aq regs.
//  2. K+V proj (512 x 64 each, shared A frags): epilogue -> LDS in the
//     verified per-head Kt/Vt layouts (head base dropped):
//       Klds: [kb=s/64][dchunk=d/8][s%64][8]
//       Vlds: [kb=s/64][keychunk=(s%64)/8][d][8]
//  3. Attention: verified attn_mfma body (wave = 32 q = 2 u-tiles),
//     K/V sourced from LDS. exp2 softmax (QSCALE pre-folded), ones-MFMA
//     row sums, PV, rcp-normalize, fast_tanh, store fp32 out.
//
// Accumulation order over K identical to R0 -> output bit-identical.
// ---------------------------------------------------------------------------
__global__ __launch_bounds__(512, 2) void fused_qkv_attn(
    const ushort* __restrict__ Xt, const ushort* __restrict__ Wt,
    const float* __restrict__ bbp, float* __restrict__ out)
{
    const int bid = blockIdx.x;               // 0..767
    const int head_lin = bid >> 1;            // b*12 + h
    const int qhalf = bid & 1;
    const int b = head_lin / NHc, h = head_lin % NHc;

    const int tid = threadIdx.x;
    const int wv = tid >> 6, lane = tid & 63;
    const int quad = lane >> 4, l16 = lane & 15;

    __shared__ __align__(16) ushort Klds[32768];   // 64 KiB; first 16384 = Q scratch
    __shared__ __align__(16) ushort Vlds[32768];   // 64 KiB
    __shared__ __align__(16) ushort Plds[8][1024]; // 16 KiB, wave-private

    const int ph  = h >> 1;                    // W panel group for this head
    const int cwb = (h & 1) * 64;              // col base within 128-col panel

    // ---------------- Phase 1: Q projection (wave = 32 q-rows) -------------
    f32x4 qacc[2][4];
    #pragma unroll
    for (int i = 0; i < 2; ++i)
        #pragma unroll
        for (int j = 0; j < 4; ++j) qacc[i][j] = (f32x4)(0.f);

    const int sq0 = qhalf * 256 + wv * 32;     // seq row base (within batch b)

    #pragma unroll 2
    for (int t = 0; t < 24; ++t) {
        const size_t kgo = (size_t)(t * 4 + quad) * 1024;
        short8v a[2], bw[4];
        #pragma unroll
        for (int i = 0; i < 2; ++i) {
            int m = b * 512 + sq0 + i * 16 + l16;
            a[i] = *(const short8v*)&Xt[(size_t)(m >> 7) * (96 * 1024) + kgo
                                        + (m & 127) * 8];
        }
        #pragma unroll
        for (int j = 0; j < 4; ++j)
            bw[j] = *(const short8v*)&Wt[(size_t)ph * (96 * 1024) + kgo
                                         + (cwb + j * 16 + l16) * 8];
        #pragma unroll
        for (int i = 0; i < 2; ++i)
            #pragma unroll
            for (int j = 0; j < 4; ++j)
                qacc[i][j] = __builtin_amdgcn_mfma_f32_16x16x32_bf16(
                    a[i], bw[j], qacc[i][j], 0, 0, 0);
    }

    // Q epilogue -> LDS scratch [q_local 256][d 64] (bf16, scaled)
    ushort* Qscr = Klds;
    #pragma unroll
    for (int j = 0; j < 4; ++j) {
        const float bias = bbp[h * 64 + j * 16 + l16];
        #pragma unroll
        for (int i = 0; i < 2; ++i) {
            const int ql = wv * 32 + i * 16 + quad * 4;   // local q base
            #pragma unroll
            for (int r = 0; r < 4; ++r)
                Qscr[(ql + r) * 64 + j * 16 + l16] =
                    f2b((qacc[i][j][r] + bias) * QSCALE);
        }
    }
    __syncthreads();

    // aq fragments (verified attn Q-frag layout), then free the scratch
    short8v aq[2][2];
    #pragma unroll
    for (int u = 0; u < 2; ++u)
        #pragma unroll
        for (int hf = 0; hf < 2; ++hf)
            aq[u][hf] = *(const short8v*)
                &Qscr[(wv * 32 + u * 16 + l16) * 64 + hf * 32 + quad * 8];
    __syncthreads();

    // ---------------- Phase 2: K + V projection (wave = 64 s-rows) ---------
    f32x4 kacc[4][4], vacc[4][4];
    #pragma unroll
    for (int i = 0; i < 4; ++i)
        #pragma unroll
        for (int j = 0; j < 4; ++j) { kacc[i][j] = (f32x4)(0.f); vacc[i][j] = (f32x4)(0.f); }

    const int sk0 = wv * 64;                   // s rows for this wave (kb = wv)

    #pragma unroll 2
    for (int t = 0; t < 24; ++t) {
        const size_t kgo = (size_t)(t * 4 + quad) * 1024;
        short8v a[4], bk_[4], bv_[4];
        #pragma unroll
        for (int i = 0; i < 4; ++i) {
            int m = b * 512 + sk0 + i * 16 + l16;
            a[i] = *(const short8v*)&Xt[(size_t)(m >> 7) * (96 * 1024) + kgo
                                        + (m & 127) * 8];
        }
        #pragma unroll
        for (int j = 0; j < 4; ++j) {
            bk_[j] = *(const short8v*)&Wt[(size_t)(6 + ph) * (96 * 1024) + kgo
                                          + (cwb + j * 16 + l16) * 8];
            bv_[j] = *(const short8v*)&Wt[(size_t)(12 + ph) * (96 * 1024) + kgo
                                          + (cwb + j * 16 + l16) * 8];
        }
        #pragma unroll
        for (int i = 0; i < 4; ++i)
            #pragma unroll
            for (int j = 0; j < 4; ++j) {
                kacc[i][j] = __builtin_amdgcn_mfma_f32_16x16x32_bf16(
                    a[i], bk_[j], kacc[i][j], 0, 0, 0);
                vacc[i][j] = __builtin_amdgcn_mfma_f32_16x16x32_bf16(
                    a[i], bv_[j], vacc[i][j], 0, 0, 0);
            }
    }

    // K/V epilogues -> LDS (verified Kt/Vt per-head layouts)
    #pragma unroll
    for (int j = 0; j < 4; ++j) {
        const int d = j * 16 + l16;
        const float biask = bbp[768 + h * 64 + d];
        const float biasv = bbp[1536 + h * 64 + d];
        #pragma unroll
        for (int i = 0; i < 4; ++i) {
            const int s0 = sk0 + i * 16 + quad * 4;
            const int baseK = (s0 >> 6) * 4096 + (d >> 3) * 512
                            + (s0 & 63) * 8 + (d & 7);
            #pragma unroll
            for (int r = 0; r < 4; ++r)
                Klds[baseK + r * 8] = f2b(kacc[i][j][r] + biask);
            const int baseV = (s0 >> 6) * 4096 + ((s0 & 63) >> 3) * 512
                            + d * 8 + (s0 & 7);
            ushort4 o4;
            o4.x = f2b(vacc[i][j][0] + biasv);
            o4.y = f2b(vacc[i][j][1] + biasv);
            o4.z = f2b(vacc[i][j][2] + biasv);
            o4.w = f2b(vacc[i][j][3] + biasv);
            *(ushort4*)&Vlds[baseV] = o4;
        }
    }
    __syncthreads();

    // ---------------- Phase 3: attention (wave = 32 q = 2 u-tiles) ---------
    const int sw = l16 & 7;                    // XOR swizzle key (verified)

    short8v ones;
    #pragma unroll
    for (int i = 0; i < 8; ++i) ones[i] = (short)0x3F80;   // bf16 1.0

    f32x4 o[2][4], rsum[2];
    #pragma unroll
    for (int u = 0; u < 2; ++u) {
        rsum[u] = (f32x4)(0.f);
        #pragma unroll
        for (int t = 0; t < 4; ++t) o[u][t] = (f32x4)(0.f);
    }

    for (int kb = 0; kb < 8; ++kb) {
        const ushort* Kb_ = Klds + kb * 4096;
        const ushort* Vb_ = Vlds + kb * 4096;

        short8v kf[4][2], vf[4][2];
        #pragma unroll
        for (int t = 0; t < 4; ++t) {
            kf[t][0] = *(const short8v*)&Kb_[quad * 512 + (t * 16 + l16) * 8];
            kf[t][1] = *(const short8v*)&Kb_[(4 + quad) * 512 + (t * 16 + l16) * 8];
            vf[t][0] = *(const short8v*)&Vb_[quad * 512 + (t * 16 + l16) * 8];
            vf[t][1] = *(const short8v*)&Vb_[(4 + quad) * 512 + (t * 16 + l16) * 8];
        }

        #pragma unroll
        for (int u = 0; u < 2; ++u) {
            // S^T: D[key=quad*4+r][q=l16]
            f32x4 sa[4];
            #pragma unroll
            for (int t = 0; t < 4; ++t) {
                f32x4 s = __builtin_amdgcn_mfma_f32_16x16x32_bf16(
                    kf[t][0], aq[u][0], (f32x4)(0.f), 0, 0, 0);
                sa[t] = __builtin_amdgcn_mfma_f32_16x16x32_bf16(
                    kf[t][1], aq[u][1], s, 0, 0, 0);
            }

            // p = exp2(s~), pack to bf16, stage to LDS (wave-private)
            #pragma unroll
            for (int t = 0; t < 4; ++t) {
                float p0 = __builtin_amdgcn_exp2f(sa[t][0]);
                float p1 = __builtin_amdgcn_exp2f(sa[t][1]);
                float p2 = __builtin_amdgcn_exp2f(sa[t][2]);
                float p3 = __builtin_amdgcn_exp2f(sa[t][3]);
                ushort2 lo = f2b2(p0, p1);
                ushort2 hi = f2b2(p2, p3);
                ushort4 pk;
                pk.x = lo.x; pk.y = lo.y; pk.z = hi.x; pk.w = hi.y;
                int c = t * 2 + (quad >> 1);            // key chunk 0..7
                int addr = l16 * 64 + ((c ^ sw) * 8) + (quad & 1) * 4;
                *(ushort4*)&Plds[wv][addr] = pk;
            }

            // P A-frags (q = l16, key chunk = hf*4+quad, swizzled)
            short8v pa0 = *(const short8v*)&Plds[wv][l16 * 64 + ((quad ^ sw) * 8)];
            short8v pa1 = *(const short8v*)&Plds[wv][l16 * 64 + (((4 + quad) ^ sw) * 8)];

            // row sums via ones-MFMA
            rsum[u] = __builtin_amdgcn_mfma_f32_16x16x32_bf16(
                pa0, ones, rsum[u], 0, 0, 0);
            rsum[u] = __builtin_amdgcn_mfma_f32_16x16x32_bf16(
                pa1, ones, rsum[u], 0, 0, 0);

            // PV: O[q=quad*4+r][d=l16]
            #pragma unroll
            for (int t2 = 0; t2 < 4; ++t2) {
                o[u][t2] = __builtin_amdgcn_mfma_f32_16x16x32_bf16(
                    pa0, vf[t2][0], o[u][t2], 0, 0, 0);
                o[u][t2] = __builtin_amdgcn_mfma_f32_16x16x32_bf16(
                    pa1, vf[t2][1], o[u][t2], 0, 0, 0);
            }
        }
    }

    // Epilogue: normalize, tanh, store fp32.
    #pragma unroll
    for (int u = 0; u < 2; ++u) {
        #pragma unroll
        for (int r = 0; r < 4; ++r) {
            float inv = __builtin_amdgcn_rcpf(rsum[u][r]);
            int q = qhalf * 256 + wv * 32 + u * 16 + quad * 4 + r;
            size_t base = ((size_t)b * Sc_ + q) * Hc + h * DHc;
            #pragma unroll
            for (int t2 = 0; t2 < 4; ++t2)
                out[base + t2 * 16 + l16] = fast_tanh(o[u][t2][r] * inv);
        }
    }
}

extern "C" void kernel_launch(void* const* d_in, const int* in_sizes, int n_in,
                              void* d_out, int out_size, void* d_ws, size_t ws_size,
                              hipStream_t stream) {
    const float* X  = (const float*)d_in[0];
    const float* Wq = (const float*)d_in[1];
    const float* bq = (const float*)d_in[2];
    const float* Wk = (const float*)d_in[3];
    const float* bk = (const float*)d_in[4];
    const float* Wv = (const float*)d_in[5];
    const float* bv = (const float*)d_in[6];
    float* out = (float*)d_out;

    // Workspace layout kept from R0 (Qb/Kt/Vt slots now unused).
    ushort* Qb  = (ushort*)d_ws;
    ushort* Kt  = Qb + (size_t)Mc * Hc;
    ushort* Vt  = Kt + (size_t)Mc * Hc;
    ushort* Xt  = Vt + (size_t)Mc * Hc;
    ushort* Wt  = Xt + (size_t)Mc * Hc;
    float*  bbp = (float*)(Wt + (size_t)Ntot * Hc);
    (void)Kt; (void)Vt;

    convert_pack<<<dim3(1752), 256, 0, stream>>>(
        X, Wq, Wk, Wv, bq, bk, bv, Xt, Wt, bbp);

    fused_qkv_attn<<<dim3(768), 512, 0, stream>>>(Xt, Wt, bbp, out);
}

// Round 7
// 222.960 us; speedup vs baseline: 1.0665x; 1.0665x over previous
//
#include <hip/hip_runtime.h>
#include <hip/hip_bf16.h>
#include <cmath>

// Problem constants
#define Bc   32
#define Sc_  512
#define Hc   768
#define NHc  12
#define DHc  64
#define Mc   (Bc * Sc_)     // 16384 tokens
#define Ntot (3 * Hc)       // 2304 fused output cols (Q|K|V)

// 0.125 (1/sqrt(DH)) * log2(e): folded into Q so softmax is exp2(s)
#define QSCALE 0.18033688011112042f

typedef __attribute__((ext_vector_type(8))) short short8v;   // 8 bf16 (4 VGPRs)
typedef __attribute__((ext_vector_type(8))) unsigned short ushort8v;
typedef __attribute__((ext_vector_type(4))) float f32x4;     // MFMA acc

static __device__ __forceinline__ ushort f2b(float f) {
    __hip_bfloat16 h = __float2bfloat16(f);
    return *reinterpret_cast<ushort*>(&h);
}
static __device__ __forceinline__ ushort2 f2b2(float a, float b) {
    __hip_bfloat162 h = __float22bfloat162_rn(float2{a, b});
    return *reinterpret_cast<ushort2*>(&h);
}

// async global->LDS, 16B per lane. HW writes lane i to (wave-uniform lds)+i*16B.
static __device__ __forceinline__ void gl2lds(const ushort* g, ushort* l) {
    __builtin_amdgcn_global_load_lds(
        (const __attribute__((address_space(1))) unsigned int*)g,
        (__attribute__((address_space(3))) unsigned int*)l, 16, 0, 0);
}

// tanh(x) = 1 - 2/(exp2(2x*log2e)+1); exact at +/-inf via rcp(inf)=0
static __device__ __forceinline__ float fast_tanh(float x) {
    float e = __builtin_amdgcn_exp2f(x * 2.885390081777927f);
    return 1.0f - 2.0f * __builtin_amdgcn_rcpf(e + 1.0f);
}

// ---------------------------------------------------------------------------
// Kernel 0 (R0 exact): fp32 -> bf16 tiled repack, coalesced both sides.
//   Xt [m/128][k/8][m%128][8], Wt [n/128][k/8][n%128][8].
// ---------------------------------------------------------------------------
__global__ __launch_bounds__(256) void convert_pack(
    const float* __restrict__ X,
    const float* __restrict__ Wq, const float* __restrict__ Wk,
    const float* __restrict__ Wv,
    const float* __restrict__ bq, const float* __restrict__ bk,
    const float* __restrict__ bv,
    ushort* __restrict__ Xt, ushort* __restrict__ Wt, float* __restrict__ bbp)
{
    const int bx = blockIdx.x;
    const int panel = bx / 12, kcg = bx % 12;   // kcg = 64-k group
    const int t = threadIdx.x;

    __shared__ ushort T[128][68];

    const float* base;
    ushort* out;
    if (panel < 128) {
        base = X + (size_t)panel * 128 * Hc;
        out  = Xt + (size_t)panel * (96 * 1024);
    } else {
        int nblk = panel - 128;                 // 0..17
        int n0 = nblk * 128;
        int z = n0 / Hc;
        int nn0 = n0 - z * Hc;
        const float* W = (z == 0) ? Wq : (z == 1) ? Wk : Wv;
        base = W + (size_t)nn0 * Hc;
        out  = Wt + (size_t)nblk * (96 * 1024);
    }
    const int k0 = kcg * 64;

    const int slot = t & 15, rsub = t >> 4;
    #pragma unroll
    for (int rnd = 0; rnd < 8; ++rnd) {
        int row = rnd * 16 + rsub;
        const float* p = base + (size_t)row * Hc + k0 + slot * 4;
        float4 f = *(const float4*)p;
        ushort2 h0 = f2b2(f.x, f.y);
        ushort2 h1 = f2b2(f.z, f.w);
        ushort4 u;
        u.x = h0.x; u.y = h0.y; u.z = h1.x; u.w = h1.y;
        *(ushort4*)&T[row][slot * 4] = u;
    }
    __syncthreads();

    const int row_w = t & 127, kh = t >> 7;
    #pragma unroll
    for (int rnd = 0; rnd < 4; ++rnd) {
        int kc_l = rnd * 2 + kh;
        ushort4 lo = *(const ushort4*)&T[row_w][kc_l * 8];
        ushort4 hi = *(const ushort4*)&T[row_w][kc_l * 8 + 4];
        ushort8v o;
        o[0] = lo.x; o[1] = lo.y; o[2] = lo.z; o[3] = lo.w;
        o[4] = hi.x; o[5] = hi.y; o[6] = hi.z; o[7] = hi.w;
        *(ushort8v*)&out[(size_t)(kcg * 8 + kc_l) * 1024 + row_w * 8] = o;
    }

    if (bx == 0) {
        for (int i = t; i < Ntot; i += 256) {
            int z2 = i / Hc, nn = i - z2 * Hc;
            bbp[i] = ((z2 == 0) ? bq : (z2 == 1) ? bk : bv)[nn];
        }
    }
}

// ---------------------------------------------------------------------------
// Kernel 1: fused QKV projection (R0 structure, BK=32, 128x128 tile).
// CHANGE vs R0: register-pressure cut to cross the 128-unified-reg occupancy
// cliff (3 -> 4 waves/SIMD = 4 blocks/CU):
//   - B fragment loaded one-at-a-time inside the j-loop (live set 20 vs 32)
//   - __launch_bounds__(256, 4) caps the allocator at 128 regs/wave
// Accumulation order per acc[i][j] unchanged -> output bit-identical to R0.
// Epilogue layouts (per head, head stride S*DH = 32768):
//   Qb: [s][d] row-major, pre-scaled by QSCALE
//   Kt: [kb=s/64][dchunk=d/8][s%64][8]
//   Vt: [kb=s/64][keychunk=(s%64)/8][d][8]
// ---------------------------------------------------------------------------
__global__ __launch_bounds__(256, 4) void qkv_mfma(
    const ushort* __restrict__ Xt, const ushort* __restrict__ Wt,
    const float* __restrict__ bbp,
    ushort* __restrict__ Qb, ushort* __restrict__ Kt, ushort* __restrict__ Vt)
{
    const int tid = threadIdx.x;
    const int wave = tid >> 6, lane = tid & 63;
    const int quad = lane >> 4, l16 = lane & 15;
    const int wr = wave >> 1, wc = wave & 1;
    const int m0 = blockIdx.x * 128;
    const int n0 = blockIdx.y * 128;

    __shared__ __align__(16) ushort As[4096];
    __shared__ __align__(16) ushort Bs[4096];

    f32x4 acc[4][4];
    #pragma unroll
    for (int i = 0; i < 4; ++i)
        #pragma unroll
        for (int j = 0; j < 4; ++j) acc[i][j] = (f32x4)(0.f);

    const ushort* gA = Xt + (size_t)blockIdx.x * (96 * 1024) + wave * 1024 + lane * 8;
    const ushort* gB = Wt + (size_t)blockIdx.y * (96 * 1024) + wave * 1024 + lane * 8;
    ushort* lA = As + wave * 1024;
    ushort* lB = Bs + wave * 1024;

    for (int t = 0; t < 24; ++t) {
        const ushort* ga = gA + t * 4096;
        const ushort* gb = gB + t * 4096;
        gl2lds(ga,       lA);
        gl2lds(ga + 512, lA + 512);
        gl2lds(gb,       lB);
        gl2lds(gb + 512, lB + 512);
        __syncthreads();

        short8v a[4];
        #pragma unroll
        for (int i = 0; i < 4; ++i)
            a[i] = *(const short8v*)&As[quad * 1024 + (wr * 64 + i * 16 + l16) * 8];
        #pragma unroll
        for (int j = 0; j < 4; ++j) {
            short8v b = *(const short8v*)&Bs[quad * 1024 + (wc * 64 + j * 16 + l16) * 8];
            #pragma unroll
            for (int i = 0; i < 4; ++i)
                acc[i][j] = __builtin_amdgcn_mfma_f32_16x16x32_bf16(
                    a[i], b, acc[i][j], 0, 0, 0);
        }
        __syncthreads();
    }

    // Epilogue. C layout per 16x16 tile: col=l16, row=quad*4+r.
    const int z = n0 / Hc;
    #pragma unroll
    for (int j = 0; j < 4; ++j) {
        const int n  = n0 + wc * 64 + j * 16 + l16;
        const int nn = n - z * Hc;
        const int h  = nn >> 6, d = nn & 63;
        const float bias = bbp[n];
        #pragma unroll
        for (int i = 0; i < 4; ++i) {
            const int mbase = m0 + wr * 64 + i * 16 + quad * 4;   // s = mbase + r
            const int bb = mbase >> 9;
            const int s0 = mbase & 511;
            const size_t head = (size_t)(bb * NHc + h) * (Sc_ * DHc);
            if (z == 0) {
                size_t base = head + (size_t)s0 * DHc + d;
                #pragma unroll
                for (int r = 0; r < 4; ++r)
                    Qb[base + (size_t)r * DHc] = f2b((acc[i][j][r] + bias) * QSCALE);
            } else if (z == 1) {
                size_t base = head + (s0 >> 6) * 4096 + (d >> 3) * 512
                            + (s0 & 63) * 8 + (d & 7);
                #pragma unroll
                for (int r = 0; r < 4; ++r)
                    Kt[base + r * 8] = f2b(acc[i][j][r] + bias);
            } else {
                size_t base = head + (s0 >> 6) * 4096 + ((s0 & 63) >> 3) * 512
                            + d * 8 + (s0 & 7);
                ushort4 o;
                o.x = f2b(acc[i][j][0] + bias);
                o.y = f2b(acc[i][j][1] + bias);
                o.z = f2b(acc[i][j][2] + bias);
                o.w = f2b(acc[i][j][3] + bias);
                *(ushort4*)&Vt[base] = o;
            }
        }
    }
}

// ---------------------------------------------------------------------------
// Kernel 2 (R0 exact): attention, 256 q per block (wave = 64 q = 4 u-tiles).
// ---------------------------------------------------------------------------
__global__ __launch_bounds__(256, 2) void attn_mfma(
    const ushort* __restrict__ Qb, const ushort* __restrict__ Kt,
    const ushort* __restrict__ Vt, float* __restrict__ out)
{
    const int bid = blockIdx.x;
    const int super = bid >> 4, l = bid & 15;
    const int head_lin = super * 8 + (l & 7);     // 0..383
    const int qhalf = l >> 3;                     // 0..1
    const int b = head_lin / NHc, h = head_lin % NHc;

    const int wave = threadIdx.x >> 6;
    const int lane = threadIdx.x & 63;
    const int quad = lane >> 4, l16 = lane & 15;
    const int q0 = qhalf * 256 + wave * 64;       // wave owns q0..q0+63
    const int sw = l16 & 7;                       // XOR swizzle key

    const size_t head = (size_t)head_lin * (Sc_ * DHc);
    const ushort* __restrict__ Q = Qb + head;
    const ushort* __restrict__ K = Kt + head;
    const ushort* __restrict__ V = Vt + head;

    __shared__ __align__(16) ushort Plds[4][1024];   // wave-private, reused per utile

    short8v aq[4][2];
    #pragma unroll
    for (int u = 0; u < 4; ++u)
        #pragma unroll
        for (int hf = 0; hf < 2; ++hf)
            aq[u][hf] = *(const short8v*)
                &Q[(size_t)(q0 + u * 16 + l16) * DHc + hf * 32 + quad * 8];

    short8v ones;
    #pragma unroll
    for (int i = 0; i < 8; ++i) ones[i] = (short)0x3F80;   // bf16 1.0

    f32x4 o[4][4], rsum[4];
    #pragma unroll
    for (int u = 0; u < 4; ++u) {
        rsum[u] = (f32x4)(0.f);
        #pragma unroll
        for (int t = 0; t < 4; ++t) o[u][t] = (f32x4)(0.f);
    }

    for (int kb = 0; kb < 8; ++kb) {
        const ushort* Kb_ = K + kb * 4096;
        const ushort* Vb_ = V + kb * 4096;

        // K/V fragments, shared by all 4 u-tiles of this wave
        short8v kf[4][2], vf[4][2];
        #pragma unroll
        for (int t = 0; t < 4; ++t) {
            kf[t][0] = *(const short8v*)&Kb_[quad * 512 + (t * 16 + l16) * 8];
            kf[t][1] = *(const short8v*)&Kb_[(4 + quad) * 512 + (t * 16 + l16) * 8];
            vf[t][0] = *(const short8v*)&Vb_[quad * 512 + (t * 16 + l16) * 8];
            vf[t][1] = *(const short8v*)&Vb_[(4 + quad) * 512 + (t * 16 + l16) * 8];
        }

        #pragma unroll
        for (int u = 0; u < 4; ++u) {
            // S^T: D[key=quad*4+r][q=l16]
            f32x4 sa[4];
            #pragma unroll
            for (int t = 0; t < 4; ++t) {
                f32x4 s = __builtin_amdgcn_mfma_f32_16x16x32_bf16(
                    kf[t][0], aq[u][0], (f32x4)(0.f), 0, 0, 0);
                sa[t] = __builtin_amdgcn_mfma_f32_16x16x32_bf16(
                    kf[t][1], aq[u][1], s, 0, 0, 0);
            }

            // p = exp2(s~), pack to bf16, stage to LDS (wave-private)
            #pragma unroll
            for (int t = 0; t < 4; ++t) {
                float p0 = __builtin_amdgcn_exp2f(sa[t][0]);
                float p1 = __builtin_amdgcn_exp2f(sa[t][1]);
                float p2 = __builtin_amdgcn_exp2f(sa[t][2]);
                float p3 = __builtin_amdgcn_exp2f(sa[t][3]);
                ushort2 lo = f2b2(p0, p1);
                ushort2 hi = f2b2(p2, p3);
                ushort4 pk;
                pk.x = lo.x; pk.y = lo.y; pk.z = hi.x; pk.w = hi.y;
                int c = t * 2 + (quad >> 1);            // key chunk 0..7
                int addr = l16 * 64 + ((c ^ sw) * 8) + (quad & 1) * 4;
                *(ushort4*)&Plds[wave][addr] = pk;
            }

            // P A-frags (q = l16, key chunk = hf*4+quad, swizzled)
            short8v pa0 = *(const short8v*)&Plds[wave][l16 * 64 + ((quad ^ sw) * 8)];
            short8v pa1 = *(const short8v*)&Plds[wave][l16 * 64 + (((4 + quad) ^ sw) * 8)];

            // row sums via ones-MFMA
            rsum[u] = __builtin_amdgcn_mfma_f32_16x16x32_bf16(
                pa0, ones, rsum[u], 0, 0, 0);
            rsum[u] = __builtin_amdgcn_mfma_f32_16x16x32_bf16(
                pa1, ones, rsum[u], 0, 0, 0);

            // PV: O[q=quad*4+r][d=l16]
            #pragma unroll
            for (int t2 = 0; t2 < 4; ++t2) {
                o[u][t2] = __builtin_amdgcn_mfma_f32_16x16x32_bf16(
                    pa0, vf[t2][0], o[u][t2], 0, 0, 0);
                o[u][t2] = __builtin_amdgcn_mfma_f32_16x16x32_bf16(
                    pa1, vf[t2][1], o[u][t2], 0, 0, 0);
            }
        }
    }

    // Epilogue: normalize, tanh, store.
    #pragma unroll
    for (int u = 0; u < 4; ++u) {
        #pragma unroll
        for (int r = 0; r < 4; ++r) {
            float inv = __builtin_amdgcn_rcpf(rsum[u][r]);
            int q = q0 + u * 16 + quad * 4 + r;
            size_t base = ((size_t)b * Sc_ + q) * Hc + h * DHc;
            #pragma unroll
            for (int t2 = 0; t2 < 4; ++t2)
                out[base + t2 * 16 + l16] = fast_tanh(o[u][t2][r] * inv);
        }
    }
}

extern "C" void kernel_launch(void* const* d_in, const int* in_sizes, int n_in,
                              void* d_out, int out_size, void* d_ws, size_t ws_size,
                              hipStream_t stream) {
    const float* X  = (const float*)d_in[0];
    const float* Wq = (const float*)d_in[1];
    const float* bq = (const float*)d_in[2];
    const float* Wk = (const float*)d_in[3];
    const float* bk = (const float*)d_in[4];
    const float* Wv = (const float*)d_in[5];
    const float* bv = (const float*)d_in[6];
    float* out = (float*)d_out;

    ushort* Qb  = (ushort*)d_ws;
    ushort* Kt  = Qb + (size_t)Mc * Hc;
    ushort* Vt  = Kt + (size_t)Mc * Hc;
    ushort* Xt  = Vt + (size_t)Mc * Hc;
    ushort* Wt  = Xt + (size_t)Mc * Hc;
    float*  bbp = (float*)(Wt + (size_t)Ntot * Hc);

    convert_pack<<<dim3(1752), 256, 0, stream>>>(
        X, Wq, Wk, Wv, bq, bk, bv, Xt, Wt, bbp);

    dim3 g1(Mc / 128, Ntot / 128);   // 128 x 18
    qkv_mfma<<<g1, 256, 0, stream>>>(Xt, Wt, bbp, Qb, Kt, Vt);

    attn_mfma<<<dim3(768), 256, 0, stream>>>(Qb, Kt, Vt, out);
}

// Round 8
// 208.766 us; speedup vs baseline: 1.1391x; 1.0680x over previous
//
#include <hip/hip_runtime.h>
#include <hip/hip_bf16.h>
#include <cmath>

// Problem constants
#define Bc   32
#define Sc_  512
#define Hc   768
#define NHc  12
#define DHc  64
#define Mc   (Bc * Sc_)     // 16384 tokens
#define Ntot (3 * Hc)       // 2304 fused output cols (Q|K|V)

// 0.125 (1/sqrt(DH)) * log2(e): folded into Q so softmax is exp2(s)
#define QSCALE 0.18033688011112042f

typedef __attribute__((ext_vector_type(8))) short short8v;   // 8 bf16 (4 VGPRs)
typedef __attribute__((ext_vector_type(8))) unsigned short ushort8v;
typedef __attribute__((ext_vector_type(4))) float f32x4;     // MFMA acc

static __device__ __forceinline__ ushort f2b(float f) {
    __hip_bfloat16 h = __float2bfloat16(f);
    return *reinterpret_cast<ushort*>(&h);
}
static __device__ __forceinline__ ushort2 f2b2(float a, float b) {
    __hip_bfloat162 h = __float22bfloat162_rn(float2{a, b});
    return *reinterpret_cast<ushort2*>(&h);
}

// async global->LDS, 16B per lane. HW writes lane i to (wave-uniform lds)+i*16B.
static __device__ __forceinline__ void gl2lds(const ushort* g, ushort* l) {
    __builtin_amdgcn_global_load_lds(
        (const __attribute__((address_space(1))) unsigned int*)g,
        (__attribute__((address_space(3))) unsigned int*)l, 16, 0, 0);
}

// tanh(x) = 1 - 2/(exp2(2x*log2e)+1); exact at +/-inf via rcp(inf)=0
static __device__ __forceinline__ float fast_tanh(float x) {
    float e = __builtin_amdgcn_exp2f(x * 2.885390081777927f);
    return 1.0f - 2.0f * __builtin_amdgcn_rcpf(e + 1.0f);
}

// ---------------------------------------------------------------------------
// Kernel 0 (R0 exact): fp32 -> bf16 tiled repack, coalesced both sides.
//   Xt [m/128][k/8][m%128][8], Wt [n/128][k/8][n%128][8].
// ---------------------------------------------------------------------------
__global__ __launch_bounds__(256) void convert_pack(
    const float* __restrict__ X,
    const float* __restrict__ Wq, const float* __restrict__ Wk,
    const float* __restrict__ Wv,
    const float* __restrict__ bq, const float* __restrict__ bk,
    const float* __restrict__ bv,
    ushort* __restrict__ Xt, ushort* __restrict__ Wt, float* __restrict__ bbp)
{
    const int bx = blockIdx.x;
    const int panel = bx / 12, kcg = bx % 12;   // kcg = 64-k group
    const int t = threadIdx.x;

    __shared__ ushort T[128][68];

    const float* base;
    ushort* out;
    if (panel < 128) {
        base = X + (size_t)panel * 128 * Hc;
        out  = Xt + (size_t)panel * (96 * 1024);
    } else {
        int nblk = panel - 128;                 // 0..17
        int n0 = nblk * 128;
        int z = n0 / Hc;
        int nn0 = n0 - z * Hc;
        const float* W = (z == 0) ? Wq : (z == 1) ? Wk : Wv;
        base = W + (size_t)nn0 * Hc;
        out  = Wt + (size_t)nblk * (96 * 1024);
    }
    const int k0 = kcg * 64;

    const int slot = t & 15, rsub = t >> 4;
    #pragma unroll
    for (int rnd = 0; rnd < 8; ++rnd) {
        int row = rnd * 16 + rsub;
        const float* p = base + (size_t)row * Hc + k0 + slot * 4;
        float4 f = *(const float4*)p;
        ushort2 h0 = f2b2(f.x, f.y);
        ushort2 h1 = f2b2(f.z, f.w);
        ushort4 u;
        u.x = h0.x; u.y = h0.y; u.z = h1.x; u.w = h1.y;
        *(ushort4*)&T[row][slot * 4] = u;
    }
    __syncthreads();

    const int row_w = t & 127, kh = t >> 7;
    #pragma unroll
    for (int rnd = 0; rnd < 4; ++rnd) {
        int kc_l = rnd * 2 + kh;
        ushort4 lo = *(const ushort4*)&T[row_w][kc_l * 8];
        ushort4 hi = *(const ushort4*)&T[row_w][kc_l * 8 + 4];
        ushort8v o;
        o[0] = lo.x; o[1] = lo.y; o[2] = lo.z; o[3] = lo.w;
        o[4] = hi.x; o[5] = hi.y; o[6] = hi.z; o[7] = hi.w;
        *(ushort8v*)&out[(size_t)(kcg * 8 + kc_l) * 1024 + row_w * 8] = o;
    }

    if (bx == 0) {
        for (int i = t; i < Ntot; i += 256) {
            int z2 = i / Hc, nn = i - z2 * Hc;
            bbp[i] = ((z2 == 0) ? bq : (z2 == 1) ? bk : bv)[nn];
        }
    }
}

// ---------------------------------------------------------------------------
// Kernel 1 (R7, kept): fused QKV projection, 128x128 tile, BK=32,
// low-VGPR variant (VGPR 64, occupancy 33%). Measured floor of the
// 2-barrier structure at this geometry (~75 us); schedule variants
// (BK=64, 256^2 8-phase, fusion) all regressed. Do not touch.
// ---------------------------------------------------------------------------
__global__ __launch_bounds__(256, 4) void qkv_mfma(
    const ushort* __restrict__ Xt, const ushort* __restrict__ Wt,
    const float* __restrict__ bbp,
    ushort* __restrict__ Qb, ushort* __restrict__ Kt, ushort* __restrict__ Vt)
{
    const int tid = threadIdx.x;
    const int wave = tid >> 6, lane = tid & 63;
    const int quad = lane >> 4, l16 = lane & 15;
    const int wr = wave >> 1, wc = wave & 1;
    const int m0 = blockIdx.x * 128;
    const int n0 = blockIdx.y * 128;

    __shared__ __align__(16) ushort As[4096];
    __shared__ __align__(16) ushort Bs[4096];

    f32x4 acc[4][4];
    #pragma unroll
    for (int i = 0; i < 4; ++i)
        #pragma unroll
        for (int j = 0; j < 4; ++j) acc[i][j] = (f32x4)(0.f);

    const ushort* gA = Xt + (size_t)blockIdx.x * (96 * 1024) + wave * 1024 + lane * 8;
    const ushort* gB = Wt + (size_t)blockIdx.y * (96 * 1024) + wave * 1024 + lane * 8;
    ushort* lA = As + wave * 1024;
    ushort* lB = Bs + wave * 1024;

    for (int t = 0; t < 24; ++t) {
        const ushort* ga = gA + t * 4096;
        const ushort* gb = gB + t * 4096;
        gl2lds(ga,       lA);
        gl2lds(ga + 512, lA + 512);
        gl2lds(gb,       lB);
        gl2lds(gb + 512, lB + 512);
        __syncthreads();

        short8v a[4];
        #pragma unroll
        for (int i = 0; i < 4; ++i)
            a[i] = *(const short8v*)&As[quad * 1024 + (wr * 64 + i * 16 + l16) * 8];
        #pragma unroll
        for (int j = 0; j < 4; ++j) {
            short8v b = *(const short8v*)&Bs[quad * 1024 + (wc * 64 + j * 16 + l16) * 8];
            #pragma unroll
            for (int i = 0; i < 4; ++i)
                acc[i][j] = __builtin_amdgcn_mfma_f32_16x16x32_bf16(
                    a[i], b, acc[i][j], 0, 0, 0);
        }
        __syncthreads();
    }

    // Epilogue. C layout per 16x16 tile: col=l16, row=quad*4+r.
    const int z = n0 / Hc;
    #pragma unroll
    for (int j = 0; j < 4; ++j) {
        const int n  = n0 + wc * 64 + j * 16 + l16;
        const int nn = n - z * Hc;
        const int h  = nn >> 6, d = nn & 63;
        const float bias = bbp[n];
        #pragma unroll
        for (int i = 0; i < 4; ++i) {
            const int mbase = m0 + wr * 64 + i * 16 + quad * 4;   // s = mbase + r
            const int bb = mbase >> 9;
            const int s0 = mbase & 511;
            const size_t head = (size_t)(bb * NHc + h) * (Sc_ * DHc);
            if (z == 0) {
                size_t base = head + (size_t)s0 * DHc + d;
                #pragma unroll
                for (int r = 0; r < 4; ++r)
                    Qb[base + (size_t)r * DHc] = f2b((acc[i][j][r] + bias) * QSCALE);
            } else if (z == 1) {
                size_t base = head + (s0 >> 6) * 4096 + (d >> 3) * 512
                            + (s0 & 63) * 8 + (d & 7);
                #pragma unroll
                for (int r = 0; r < 4; ++r)
                    Kt[base + r * 8] = f2b(acc[i][j][r] + bias);
            } else {
                size_t base = head + (s0 >> 6) * 4096 + ((s0 & 63) >> 3) * 512
                            + d * 8 + (s0 & 7);
                ushort4 o;
                o.x = f2b(acc[i][j][0] + bias);
                o.y = f2b(acc[i][j][1] + bias);
                o.z = f2b(acc[i][j][2] + bias);
                o.w = f2b(acc[i][j][3] + bias);
                *(ushort4*)&Vt[base] = o;
            }
        }
    }
}

// ---------------------------------------------------------------------------
// Kernel 2 (NEW): attention, 128 q per block (wave = 32 q = 2 u-tiles),
// 1536 blocks (4 per head, same-head on one XCD via swizzle).
// Register diet for 4 waves/SIMD (2x the old occupancy):
//   - K/V time-share: kf live only in QK phase; vf loaded after last kf use
//     (both u-tiles' P buffered in wave-private LDS), so kf/vf never coexist.
//   - o[2][4]+rsum[2] = 40 acc regs (was 80).
//   - __launch_bounds__(256, 4) targets the <=128-reg class.
// Per-q MFMA sequence and accumulation order identical -> bit-identical out.
// ---------------------------------------------------------------------------
__global__ __launch_bounds__(256, 4) void attn_mfma(
    const ushort* __restrict__ Qb, const ushort* __restrict__ Kt,
    const ushort* __restrict__ Vt, float* __restrict__ out)
{
    const int bid = blockIdx.x;
    const int super = bid >> 5, l = bid & 31;
    const int head_lin = super * 8 + (l & 7);     // 0..383
    const int qq = l >> 3;                        // q-quarter 0..3
    const int b = head_lin / NHc, h = head_lin % NHc;

    const int wave = threadIdx.x >> 6;
    const int lane = threadIdx.x & 63;
    const int quad = lane >> 4, l16 = lane & 15;
    const int q0 = qq * 128 + wave * 32;          // wave owns q0..q0+31
    const int sw = l16 & 7;                       // XOR swizzle key

    const size_t head = (size_t)head_lin * (Sc_ * DHc);
    const ushort* __restrict__ Q = Qb + head;
    const ushort* __restrict__ K = Kt + head;
    const ushort* __restrict__ V = Vt + head;

    __shared__ __align__(16) ushort Plds[4][2048];   // wave-private, 2 u-tiles

    short8v aq[2][2];
    #pragma unroll
    for (int u = 0; u < 2; ++u)
        #pragma unroll
        for (int hf = 0; hf < 2; ++hf)
            aq[u][hf] = *(const short8v*)
                &Q[(size_t)(q0 + u * 16 + l16) * DHc + hf * 32 + quad * 8];

    short8v ones;
    #pragma unroll
    for (int i = 0; i < 8; ++i) ones[i] = (short)0x3F80;   // bf16 1.0

    f32x4 o[2][4], rsum[2];
    #pragma unroll
    for (int u = 0; u < 2; ++u) {
        rsum[u] = (f32x4)(0.f);
        #pragma unroll
        for (int t = 0; t < 4; ++t) o[u][t] = (f32x4)(0.f);
    }

    for (int kb = 0; kb < 8; ++kb) {
        const ushort* Kb_ = K + kb * 4096;
        const ushort* Vb_ = V + kb * 4096;

        // ---- QK phase: only kf live ----
        {
            short8v kf[4][2];
            #pragma unroll
            for (int t = 0; t < 4; ++t) {
                kf[t][0] = *(const short8v*)&Kb_[quad * 512 + (t * 16 + l16) * 8];
                kf[t][1] = *(const short8v*)&Kb_[(4 + quad) * 512 + (t * 16 + l16) * 8];
            }

            #pragma unroll
            for (int u = 0; u < 2; ++u) {
                // S^T: D[key=quad*4+r][q=l16]
                f32x4 sa[4];
                #pragma unroll
                for (int t = 0; t < 4; ++t) {
                    f32x4 s = __builtin_amdgcn_mfma_f32_16x16x32_bf16(
                        kf[t][0], aq[u][0], (f32x4)(0.f), 0, 0, 0);
                    sa[t] = __builtin_amdgcn_mfma_f32_16x16x32_bf16(
                        kf[t][1], aq[u][1], s, 0, 0, 0);
                }

                // p = exp2(s~), pack to bf16, stage to LDS (wave-private)
                #pragma unroll
                for (int t = 0; t < 4; ++t) {
                    float p0 = __builtin_amdgcn_exp2f(sa[t][0]);
                    float p1 = __builtin_amdgcn_exp2f(sa[t][1]);
                    float p2 = __builtin_amdgcn_exp2f(sa[t][2]);
                    float p3 = __builtin_amdgcn_exp2f(sa[t][3]);
                    ushort2 lo = f2b2(p0, p1);
                    ushort2 hi = f2b2(p2, p3);
                    ushort4 pk;
                    pk.x = lo.x; pk.y = lo.y; pk.z = hi.x; pk.w = hi.y;
                    int c = t * 2 + (quad >> 1);            // key chunk 0..7
                    int addr = u * 1024 + l16 * 64 + ((c ^ sw) * 8) + (quad & 1) * 4;
                    *(ushort4*)&Plds[wave][addr] = pk;
                }
            }
        }

        // ---- PV phase: only vf live (re-uses kf's registers) ----
        {
            short8v vf[4][2];
            #pragma unroll
            for (int t = 0; t < 4; ++t) {
                vf[t][0] = *(const short8v*)&Vb_[quad * 512 + (t * 16 + l16) * 8];
                vf[t][1] = *(const short8v*)&Vb_[(4 + quad) * 512 + (t * 16 + l16) * 8];
            }

            #pragma unroll
            for (int u = 0; u < 2; ++u) {
                // P A-frags (q = l16, key chunk = hf*4+quad, swizzled)
                short8v pa0 = *(const short8v*)
                    &Plds[wave][u * 1024 + l16 * 64 + ((quad ^ sw) * 8)];
                short8v pa1 = *(const short8v*)
                    &Plds[wave][u * 1024 + l16 * 64 + (((4 + quad) ^ sw) * 8)];

                // row sums via ones-MFMA
                rsum[u] = __builtin_amdgcn_mfma_f32_16x16x32_bf16(
                    pa0, ones, rsum[u], 0, 0, 0);
                rsum[u] = __builtin_amdgcn_mfma_f32_16x16x32_bf16(
                    pa1, ones, rsum[u], 0, 0, 0);

                // PV: O[q=quad*4+r][d=l16]
                #pragma unroll
                for (int t2 = 0; t2 < 4; ++t2) {
                    o[u][t2] = __builtin_amdgcn_mfma_f32_16x16x32_bf16(
                        pa0, vf[t2][0], o[u][t2], 0, 0, 0);
                    o[u][t2] = __builtin_amdgcn_mfma_f32_16x16x32_bf16(
                        pa1, vf[t2][1], o[u][t2], 0, 0, 0);
                }
            }
        }
    }

    // Epilogue: normalize, tanh, store.
    #pragma unroll
    for (int u = 0; u < 2; ++u) {
        #pragma unroll
        for (int r = 0; r < 4; ++r) {
            float inv = __builtin_amdgcn_rcpf(rsum[u][r]);
            int q = q0 + u * 16 + quad * 4 + r;
            size_t base = ((size_t)b * Sc_ + q) * Hc + h * DHc;
            #pragma unroll
            for (int t2 = 0; t2 < 4; ++t2)
                out[base + t2 * 16 + l16] = fast_tanh(o[u][t2][r] * inv);
        }
    }
}

extern "C" void kernel_launch(void* const* d_in, const int* in_sizes, int n_in,
                              void* d_out, int out_size, void* d_ws, size_t ws_size,
                              hipStream_t stream) {
    const float* X  = (const float*)d_in[0];
    const float* Wq = (const float*)d_in[1];
    const float* bq = (const float*)d_in[2];
    const float* Wk = (const float*)d_in[3];
    const float* bk = (const float*)d_in[4];
    const float* Wv = (const float*)d_in[5];
    const float* bv = (const float*)d_in[6];
    float* out = (float*)d_out;

    ushort* Qb  = (ushort*)d_ws;
    ushort* Kt  = Qb + (size_t)Mc * Hc;
    ushort* Vt  = Kt + (size_t)Mc * Hc;
    ushort* Xt  = Vt + (size_t)Mc * Hc;
    ushort* Wt  = Xt + (size_t)Mc * Hc;
    float*  bbp = (float*)(Wt + (size_t)Ntot * Hc);

    convert_pack<<<dim3(1752), 256, 0, stream>>>(
        X, Wq, Wk, Wv, bq, bk, bv, Xt, Wt, bbp);

    dim3 g1(Mc / 128, Ntot / 128);   // 128 x 18
    qkv_mfma<<<g1, 256, 0, stream>>>(Xt, Wt, bbp, Qb, Kt, Vt);

    attn_mfma<<<dim3(1536), 256, 0, stream>>>(Qb, Kt, Vt, out);
}